// Round 1
// baseline (466.551 us; speedup 1.0000x reference)
//
#include <hip/hip_runtime.h>
#include <math.h>

typedef unsigned long long u64;
typedef unsigned int u32;

#define NB 16
#define SL 1024
#define DIM 16
#define MDIM 16
#define KNN 8
#define EIN 33   /* 2*DIM+1 */
#define EH 66    /* edge hidden */
#define CH 64    /* coors hidden */
#define NHID 32  /* node hidden */
#define NINDIM 32
#define LN_EPS 1e-5f

__device__ __forceinline__ float silu_f(float x) {
    return x / (1.0f + expf(-x));
}

// ---------------- init: feats = token_emb[residues] + pos_emb; copy coords ----------------
__global__ __launch_bounds__(256) void init_kernel(
    const float* __restrict__ coords, const int* __restrict__ residues,
    const float* __restrict__ token_emb, const float* __restrict__ pos_emb,
    float* __restrict__ coordsA, float* __restrict__ featsA)
{
    const int nid = blockIdx.x * 256 + threadIdx.x;   // 0 .. NB*SL-1
    if (nid >= NB * SL) return;
    const int l = nid & (SL - 1);
    const int r = residues[nid];
#pragma unroll
    for (int c = 0; c < DIM; ++c)
        featsA[nid * DIM + c] = token_emb[r * DIM + c] + pos_emb[l * DIM + c];
#pragma unroll
    for (int c = 0; c < 3; ++c)
        coordsA[nid * 3 + c] = coords[nid * 3 + c];
}

// ---------------- kNN: one wave per query node ----------------
#define CSWAP(x, y) { bool lt = lst[x] < lst[y]; u64 mn = lt ? lst[x] : lst[y]; u64 mx = lt ? lst[y] : lst[x]; lst[x] = mn; lst[y] = mx; }

__global__ __launch_bounds__(256) void knn_kernel(
    const float* __restrict__ coords, const int* __restrict__ lengths,
    int* __restrict__ idxbuf)
{
    const int wv = threadIdx.x >> 6;
    const int lane = threadIdx.x & 63;
    const int nid = blockIdx.x * 4 + wv;
    const int b = nid >> 10;
    const int i = nid & (SL - 1);
    const int len = lengths[b];
    const bool mi = i < len;
    const float* cb = coords + (size_t)b * SL * 3;
    const float xi = cb[i * 3 + 0], yi = cb[i * 3 + 1], zi = cb[i * 3 + 2];

    u64 lst[8];
#pragma unroll
    for (int t = 0; t < 8; ++t) lst[t] = 0xFFFFFFFFFFFFFFFFull;

    for (int j0 = 0; j0 < SL; j0 += 64) {
        const int j = j0 + lane;
        const float xj = cb[j * 3 + 0], yj = cb[j * 3 + 1], zj = cb[j * 3 + 2];
        // strict IEEE mul/add, no contraction: match numpy (d0*d0 + d1*d1) + d2*d2
        const float dx = __fsub_rn(xi, xj), dy = __fsub_rn(yi, yj), dz = __fsub_rn(zi, zj);
        const float dist = __fadd_rn(__fadd_rn(__fmul_rn(dx, dx), __fmul_rn(dy, dy)), __fmul_rn(dz, dz));
        const bool pm = mi && (j < len);
        float v = pm ? dist : 1e5f;
        if (j == i) v = -1.0f;
        else if (pm && (j == i + 1 || j + 1 == i)) v = 0.0f;
        // order-preserving float->uint, pack with index for lexicographic tiebreak
        u32 bits = __float_as_uint(v);
        bits ^= (bits & 0x80000000u) ? 0xFFFFFFFFu : 0x80000000u;
        const u64 key = ((u64)bits << 32) | (u32)j;
        // insert into sorted-ascending 8-list (predicated shift)
#pragma unroll
        for (int p = 7; p >= 1; --p)
            lst[p] = (key < lst[p]) ? ((key < lst[p - 1]) ? lst[p - 1] : key) : lst[p];
        lst[0] = (key < lst[0]) ? key : lst[0];
    }

    // butterfly merge across 64 lanes: min-of-reversed + bitonic-8 resort
#pragma unroll
    for (int m = 1; m < 64; m <<= 1) {
        u64 o[8];
#pragma unroll
        for (int t = 0; t < 8; ++t) o[t] = __shfl_xor(lst[7 - t], m, 64);
#pragma unroll
        for (int t = 0; t < 8; ++t) lst[t] = (lst[t] < o[t]) ? lst[t] : o[t];
        CSWAP(0, 4) CSWAP(1, 5) CSWAP(2, 6) CSWAP(3, 7)
        CSWAP(0, 2) CSWAP(1, 3) CSWAP(4, 6) CSWAP(5, 7)
        CSWAP(0, 1) CSWAP(2, 3) CSWAP(4, 5) CSWAP(6, 7)
    }

    if (lane == 0) {
#pragma unroll
        for (int t = 0; t < 8; ++t)
            idxbuf[nid * KNN + t] = (int)(u32)(lst[t] & 0xFFFFFFFFull);
    }
}

// ---------------- one EGNN layer: one wave per node, 4 nodes/block ----------------
__global__ __launch_bounds__(256) void layer_kernel(
    const int d,
    const float* __restrict__ coordsIn, float* __restrict__ coordsOut,
    const float* __restrict__ featsIn, float* __restrict__ featsOut,
    const int* __restrict__ idxbuf, const int* __restrict__ lengths,
    const float* __restrict__ g_ew1, const float* __restrict__ g_eb1,
    const float* __restrict__ g_ew2, const float* __restrict__ g_eb2,
    const float* __restrict__ g_cw1, const float* __restrict__ g_cb1,
    const float* __restrict__ g_cw2, const float* __restrict__ g_cb2,
    const float* __restrict__ g_lng, const float* __restrict__ g_lnb,
    const float* __restrict__ g_nw1, const float* __restrict__ g_nb1,
    const float* __restrict__ g_nw2, const float* __restrict__ g_nb2)
{
    // layer weights (shared by all 4 waves)
    __shared__ float s_ew1[EIN * EH];
    __shared__ float s_eb1[EH];
    __shared__ float s_ew2[EH * MDIM];
    __shared__ float s_eb2[MDIM];
    __shared__ float s_cw1[MDIM * CH];
    __shared__ float s_cb1[CH];
    __shared__ float s_cw2[CH];
    __shared__ float s_cb2;
    __shared__ float s_lng[DIM], s_lnb[DIM];
    __shared__ float s_nw1[NINDIM * NHID];
    __shared__ float s_nb1[NHID];
    __shared__ float s_nw2[NHID * DIM];
    __shared__ float s_nb2[DIM];
    // per-wave scratch (padded to 17 where k-strided reads occur)
    __shared__ float s_fi[4][DIM];
    __shared__ float s_ci[4][3];
    __shared__ float s_fj[4][KNN][17];
    __shared__ float s_rel[4][KNN][3];
    __shared__ float s_rd[4][KNN];
    __shared__ int   s_em[4][KNN];
    __shared__ float s_h[4][KNN][EH];
    __shared__ float s_m[4][KNN][17];
    __shared__ float s_w[4][KNN];
    __shared__ float s_mi[4][MDIM];
    __shared__ float s_nin[4][NINDIM];
    __shared__ float s_nh[4][NHID];

    const int tid = threadIdx.x;
    for (int t = tid; t < EIN * EH; t += 256) s_ew1[t] = g_ew1[d * EIN * EH + t];
    for (int t = tid; t < EH; t += 256) s_eb1[t] = g_eb1[d * EH + t];
    for (int t = tid; t < EH * MDIM; t += 256) s_ew2[t] = g_ew2[d * EH * MDIM + t];
    for (int t = tid; t < MDIM; t += 256) s_eb2[t] = g_eb2[d * MDIM + t];
    for (int t = tid; t < MDIM * CH; t += 256) s_cw1[t] = g_cw1[d * MDIM * CH + t];
    for (int t = tid; t < CH; t += 256) s_cb1[t] = g_cb1[d * CH + t];
    for (int t = tid; t < CH; t += 256) s_cw2[t] = g_cw2[d * CH + t];
    if (tid == 0) s_cb2 = g_cb2[d];
    for (int t = tid; t < DIM; t += 256) { s_lng[t] = g_lng[d * DIM + t]; s_lnb[t] = g_lnb[d * DIM + t]; }
    for (int t = tid; t < NINDIM * NHID; t += 256) s_nw1[t] = g_nw1[d * NINDIM * NHID + t];
    for (int t = tid; t < NHID; t += 256) s_nb1[t] = g_nb1[d * NHID + t];
    for (int t = tid; t < NHID * DIM; t += 256) s_nw2[t] = g_nw2[d * NHID * DIM + t];
    for (int t = tid; t < DIM; t += 256) s_nb2[t] = g_nb2[d * DIM + t];

    const int wv = tid >> 6;
    const int lane = tid & 63;
    const int nid = blockIdx.x * 4 + wv;
    const int b = nid >> 10;
    const int i = nid & (SL - 1);
    const int len = lengths[b];
    const bool mski = i < len;

    // per-node gathers
    if (lane < DIM) s_fi[wv][lane] = featsIn[(size_t)nid * DIM + lane];
    if (lane < 3)   s_ci[wv][lane] = coordsIn[(size_t)nid * 3 + lane];
    {
        const int k = lane >> 4;        // 0..3
        const int c = lane & 15;
        const int j0 = idxbuf[nid * KNN + k];
        s_fj[wv][k][c] = featsIn[((size_t)b * SL + j0) * DIM + c];
        const int j1 = idxbuf[nid * KNN + k + 4];
        s_fj[wv][k + 4][c] = featsIn[((size_t)b * SL + j1) * DIM + c];
    }
    if (lane < KNN) {
        const int j = idxbuf[nid * KNN + lane];
        const float xi = coordsIn[(size_t)nid * 3 + 0];
        const float yi = coordsIn[(size_t)nid * 3 + 1];
        const float zi = coordsIn[(size_t)nid * 3 + 2];
        const float xj = coordsIn[((size_t)b * SL + j) * 3 + 0];
        const float yj = coordsIn[((size_t)b * SL + j) * 3 + 1];
        const float zj = coordsIn[((size_t)b * SL + j) * 3 + 2];
        const float rx = __fsub_rn(xi, xj), ry = __fsub_rn(yi, yj), rz = __fsub_rn(zi, zj);
        s_rel[wv][lane][0] = rx; s_rel[wv][lane][1] = ry; s_rel[wv][lane][2] = rz;
        s_rd[wv][lane] = __fadd_rn(__fadd_rn(__fmul_rn(rx, rx), __fmul_rn(ry, ry)), __fmul_rn(rz, rz));
        s_em[wv][lane] = (mski && j < len) ? 1 : 0;
    }
    __syncthreads();

    // --- edge MLP layer 1: h[k][u] = silu(edge_in[k] . ew1[:,u] + eb1[u]) ---
    {
        const int k = lane >> 3;
        const int s = lane & 7;
        float acc[9];
#pragma unroll
        for (int t = 0; t < 9; ++t) {
            const int u = s + 8 * t;
            acc[t] = (u < EH) ? s_eb1[u] : 0.0f;
        }
#pragma unroll
        for (int c = 0; c < DIM; ++c) {
            const float e = s_fi[wv][c];
            const float* wr = &s_ew1[c * EH];
#pragma unroll
            for (int t = 0; t < 9; ++t) {
                const int u = s + 8 * t;
                if (u < EH) acc[t] = fmaf(e, wr[u], acc[t]);
            }
        }
#pragma unroll
        for (int c = 0; c < DIM; ++c) {
            const float e = s_fj[wv][k][c];
            const float* wr = &s_ew1[(DIM + c) * EH];
#pragma unroll
            for (int t = 0; t < 9; ++t) {
                const int u = s + 8 * t;
                if (u < EH) acc[t] = fmaf(e, wr[u], acc[t]);
            }
        }
        {
            const float e = s_rd[wv][k];
            const float* wr = &s_ew1[(2 * DIM) * EH];
#pragma unroll
            for (int t = 0; t < 9; ++t) {
                const int u = s + 8 * t;
                if (u < EH) acc[t] = fmaf(e, wr[u], acc[t]);
            }
        }
#pragma unroll
        for (int t = 0; t < 9; ++t) {
            const int u = s + 8 * t;
            if (u < EH) s_h[wv][k][u] = silu_f(acc[t]);
        }
    }
    __syncthreads();

    // --- edge MLP layer 2: m[k][u] = silu(h[k] . ew2[:,u] + eb2[u]) ---
    {
        const int k = lane >> 3;
        const int s = lane & 7;
        float a0 = s_eb2[s], a1 = s_eb2[s + 8];
#pragma unroll
        for (int c = 0; c < EH; ++c) {
            const float e = s_h[wv][k][c];
            a0 = fmaf(e, s_ew2[c * MDIM + s], a0);
            a1 = fmaf(e, s_ew2[c * MDIM + s + 8], a1);
        }
        s_m[wv][k][s] = silu_f(a0);
        s_m[wv][k][s + 8] = silu_f(a1);
    }
    __syncthreads();

    // --- coors MLP: w[k] = silu(m[k] @ cw1 + cb1) @ cw2 + cb2, masked ---
    {
        const int k = lane >> 3;
        const int s = lane & 7;
        float acc[8];
#pragma unroll
        for (int t = 0; t < 8; ++t) acc[t] = s_cb1[s + 8 * t];
#pragma unroll
        for (int c = 0; c < MDIM; ++c) {
            const float e = s_m[wv][k][c];
#pragma unroll
            for (int t = 0; t < 8; ++t) acc[t] = fmaf(e, s_cw1[c * CH + s + 8 * t], acc[t]);
        }
        float partial = 0.0f;
#pragma unroll
        for (int t = 0; t < 8; ++t) partial = fmaf(silu_f(acc[t]), s_cw2[s + 8 * t], partial);
#pragma unroll
        for (int m = 1; m < 8; m <<= 1) partial += __shfl_xor(partial, m, 64);
        if (s == 0) s_w[wv][k] = s_em[wv][k] ? (partial + s_cb2) : 0.0f;
    }
    __syncthreads();

    // --- coord update (lanes 0..2) and masked m_i (lanes 8..23) ---
    if (lane < 3) {
        float cc = s_ci[wv][lane];
#pragma unroll
        for (int k = 0; k < KNN; ++k) cc = fmaf(s_w[wv][k], s_rel[wv][k][lane], cc);
        coordsOut[(size_t)nid * 3 + lane] = cc;
    }
    if (lane >= 8 && lane < 8 + MDIM) {
        const int c = lane - 8;
        float acc = 0.0f;
#pragma unroll
        for (int k = 0; k < KNN; ++k) acc += s_em[wv][k] ? s_m[wv][k][c] : 0.0f;
        s_mi[wv][c] = acc;
    }
    __syncthreads();

    // --- LayerNorm(feats) and concat with m_i ---
    if (lane < DIM) {
        float mu = 0.0f;
#pragma unroll
        for (int c = 0; c < DIM; ++c) mu += s_fi[wv][c];
        mu *= (1.0f / 16.0f);
        float var = 0.0f;
#pragma unroll
        for (int c = 0; c < DIM; ++c) { const float dd = s_fi[wv][c] - mu; var += dd * dd; }
        var *= (1.0f / 16.0f);
        const float nrm = (s_fi[wv][lane] - mu) / sqrtf(var + LN_EPS);
        s_nin[wv][lane] = nrm * s_lng[lane] + s_lnb[lane];
    } else if (lane < 2 * DIM) {
        s_nin[wv][lane] = s_mi[wv][lane - DIM];
    }
    __syncthreads();

    // --- node MLP hidden ---
    if (lane < NHID) {
        float acc = s_nb1[lane];
#pragma unroll
        for (int c = 0; c < NINDIM; ++c) acc = fmaf(s_nin[wv][c], s_nw1[c * NHID + lane], acc);
        s_nh[wv][lane] = silu_f(acc);
    }
    __syncthreads();

    // --- node MLP out + residual ---
    if (lane < DIM) {
        float acc = s_nb2[lane];
#pragma unroll
        for (int c = 0; c < NHID; ++c) acc = fmaf(s_nh[wv][c], s_nw2[c * DIM + lane], acc);
        featsOut[(size_t)nid * DIM + lane] = s_fi[wv][lane] + acc;
    }
}

// ---------------- final projection ----------------
__global__ __launch_bounds__(256) void final_kernel(
    const float* __restrict__ feats, const float* __restrict__ fw,
    const float* __restrict__ fb, float* __restrict__ out)
{
    const int nid = blockIdx.x * 256 + threadIdx.x;
    if (nid >= NB * SL) return;
    float f[DIM];
#pragma unroll
    for (int c = 0; c < DIM; ++c) f[c] = feats[nid * DIM + c];
#pragma unroll
    for (int o = 0; o < 3; ++o) {
        float acc = fb[o];
#pragma unroll
        for (int c = 0; c < DIM; ++c) acc = fmaf(f[c], fw[c * 3 + o], acc);
        out[nid * 3 + o] = acc;
    }
}

extern "C" void kernel_launch(void* const* d_in, const int* in_sizes, int n_in,
                              void* d_out, int out_size, void* d_ws, size_t ws_size,
                              hipStream_t stream) {
    const float* coords    = (const float*)d_in[0];
    const int*   residues  = (const int*)d_in[1];
    const int*   lengths   = (const int*)d_in[2];
    const float* token_emb = (const float*)d_in[3];
    const float* pos_emb   = (const float*)d_in[4];
    const float* ew1 = (const float*)d_in[5];
    const float* eb1 = (const float*)d_in[6];
    const float* ew2 = (const float*)d_in[7];
    const float* eb2 = (const float*)d_in[8];
    const float* cw1 = (const float*)d_in[9];
    const float* cb1 = (const float*)d_in[10];
    const float* cw2 = (const float*)d_in[11];
    const float* cb2 = (const float*)d_in[12];
    const float* lng = (const float*)d_in[13];
    const float* lnb = (const float*)d_in[14];
    const float* nw1 = (const float*)d_in[15];
    const float* nb1 = (const float*)d_in[16];
    const float* nw2 = (const float*)d_in[17];
    const float* nb2 = (const float*)d_in[18];
    const float* fw  = (const float*)d_in[19];
    const float* fb  = (const float*)d_in[20];

    float* ws = (float*)d_ws;
    float* coordsA = ws;                          // NB*SL*3
    float* coordsB = coordsA + NB * SL * 3;       // NB*SL*3
    float* featsA  = coordsB + NB * SL * 3;       // NB*SL*DIM
    float* featsB  = featsA + NB * SL * DIM;      // NB*SL*DIM
    int*   idxbuf  = (int*)(featsB + NB * SL * DIM); // NB*SL*KNN

    init_kernel<<<NB * SL / 256, 256, 0, stream>>>(coords, residues, token_emb, pos_emb, coordsA, featsA);

    float* cIn = coordsA; float* cOut = coordsB;
    float* fIn = featsA;  float* fOut = featsB;
    for (int d = 0; d < 3; ++d) {
        knn_kernel<<<NB * SL / 4, 256, 0, stream>>>(cIn, lengths, idxbuf);
        layer_kernel<<<NB * SL / 4, 256, 0, stream>>>(d, cIn, cOut, fIn, fOut, idxbuf, lengths,
            ew1, eb1, ew2, eb2, cw1, cb1, cw2, cb2, lng, lnb, nw1, nb1, nw2, nb2);
        float* t;
        t = cIn; cIn = cOut; cOut = t;
        t = fIn; fIn = fOut; fOut = t;
    }

    final_kernel<<<NB * SL / 256, 256, 0, stream>>>(fIn, fw, fb, (float*)d_out);
}

// Round 2
// 356.797 us; speedup vs baseline: 1.3076x; 1.3076x over previous
//
#include <hip/hip_runtime.h>
#include <math.h>

typedef unsigned long long u64;
typedef unsigned int u32;

#define NB 16
#define SL 1024
#define DIM 16
#define MDIM 16
#define KNN 8
#define EH 66    /* edge hidden */
#define CH 64    /* coors hidden */
#define NHID 32  /* node hidden */
#define LN_EPS 1e-5f
#define W1T_STRIDE 36   /* 33 padded to 16B multiple */

__device__ __forceinline__ float silu_f(float x) {
    return x / (1.0f + __expf(-x));
}

// ---------------- init: feats = token_emb[residues] + pos_emb; copy coords ----------------
__global__ __launch_bounds__(256) void init_kernel(
    const float* __restrict__ coords, const int* __restrict__ residues,
    const float* __restrict__ token_emb, const float* __restrict__ pos_emb,
    float* __restrict__ coordsA, float* __restrict__ featsA)
{
    const int nid = blockIdx.x * 256 + threadIdx.x;
    if (nid >= NB * SL) return;
    const int l = nid & (SL - 1);
    const int r = residues[nid];
#pragma unroll
    for (int c = 0; c < DIM; ++c)
        featsA[nid * DIM + c] = token_emb[r * DIM + c] + pos_emb[l * DIM + c];
#pragma unroll
    for (int c = 0; c < 3; ++c)
        coordsA[nid * 3 + c] = coords[nid * 3 + c];
}

// ---------------- weight transpose/pack (runs every launch; idempotent) ----------------
__global__ __launch_bounds__(256) void pack_kernel(
    const float* __restrict__ ew1, const float* __restrict__ cw1,
    const float* __restrict__ nw1, const float* __restrict__ nw2,
    float* __restrict__ w1t, float* __restrict__ cw1t,
    float* __restrict__ nw1t, float* __restrict__ nw2t)
{
    const int stride = gridDim.x * 256;
    const int t0 = blockIdx.x * 256 + threadIdx.x;
    // w1t[d][u][c] = ew1[d][c][u]   (33x66 -> 66 rows of 33, stride 36)
    for (int idx = t0; idx < 3 * EH * 33; idx += stride) {
        int d = idx / (EH * 33); int r = idx - d * EH * 33; int u = r / 33; int c = r - u * 33;
        w1t[(d * EH + u) * W1T_STRIDE + c] = ew1[(d * 33 + c) * EH + u];
    }
    // cw1t[d][t][v] = cw1[d][v][t]  (16x64 -> 64 rows of 16)
    for (int idx = t0; idx < 3 * CH * 16; idx += stride) {
        int d = idx / (CH * 16); int r = idx - d * CH * 16; int t = r >> 4; int v = r & 15;
        cw1t[(d * CH + t) * 16 + v] = cw1[(d * 16 + v) * CH + t];
    }
    // nw1t[d][u][c] = nw1[d][c][u]  (32x32 -> 32 rows of 32)
    for (int idx = t0; idx < 3 * NHID * 32; idx += stride) {
        int d = idx / (NHID * 32); int r = idx - d * NHID * 32; int u = r >> 5; int c = r & 31;
        nw1t[(d * NHID + u) * 32 + c] = nw1[(d * 32 + c) * NHID + u];
    }
    // nw2t[d][c][u] = nw2[d][u][c]  (32x16 -> 16 rows of 32)
    for (int idx = t0; idx < 3 * 16 * 32; idx += stride) {
        int d = idx / (16 * 32); int r = idx - d * 16 * 32; int c = r >> 5; int u = r & 31;
        nw2t[(d * 16 + c) * 32 + u] = nw2[(d * 32 + u) * 16 + c];
    }
}

// ---------------- kNN: one wave per query node, u32 packed keys ----------------
#define CSU(x, y) { u32 mn = min(lst[x], lst[y]); u32 mx = max(lst[x], lst[y]); lst[x] = mn; lst[y] = mx; }

__global__ __launch_bounds__(256) void knn_kernel(
    const float* __restrict__ coords, const int* __restrict__ lengths,
    int* __restrict__ idxbuf)
{
    const int wv = threadIdx.x >> 6;
    const int lane = threadIdx.x & 63;
    const int nid = blockIdx.x * 4 + wv;
    const int b = nid >> 10;
    const int i = nid & (SL - 1);
    const int len = lengths[b];
    const bool mi = i < len;
    const float* cb = coords + (size_t)b * SL * 3;
    const float xi = cb[i * 3 + 0], yi = cb[i * 3 + 1], zi = cb[i * 3 + 2];

    u32 lst[8];
#pragma unroll
    for (int t = 0; t < 8; ++t) lst[t] = 0xFFFFFFFFu;

    for (int j0 = 0; j0 < SL; j0 += 64) {
        const int j = j0 + lane;
        const float xj = cb[j * 3 + 0], yj = cb[j * 3 + 1], zj = cb[j * 3 + 2];
        // strict IEEE, no contraction: match numpy (d0*d0 + d1*d1) + d2*d2
        const float dx = __fsub_rn(xi, xj), dy = __fsub_rn(yi, yj), dz = __fsub_rn(zi, zj);
        const float dist = __fadd_rn(__fadd_rn(__fmul_rn(dx, dx), __fmul_rn(dy, dy)), __fmul_rn(dz, dz));
        const bool pm = mi && (j < len);
        float v = pm ? dist : 1e5f;
        if (j == i) v = -1.0f;
        else if (pm && (j == i + 1 || j + 1 == i)) v = 0.0f;
        // order-preserving float->u32, top 22 bits + 10-bit index (set-equivalent tiebreak)
        u32 bits = __float_as_uint(v);
        bits ^= (bits & 0x80000000u) ? 0xFFFFFFFFu : 0x80000000u;
        const u32 key = (bits & 0xFFFFFC00u) | (u32)j;
        // predicated insertion into ascending 8-list
#pragma unroll
        for (int p = 7; p >= 1; --p)
            lst[p] = (key < lst[p]) ? ((key < lst[p - 1]) ? lst[p - 1] : key) : lst[p];
        lst[0] = (key < lst[0]) ? key : lst[0];
    }

    // butterfly merge: min-of-reversed + bitonic-8 resort (u32 min/max)
#pragma unroll
    for (int s = 1; s < 64; s <<= 1) {
        u32 o[8];
#pragma unroll
        for (int t = 0; t < 8; ++t) o[t] = (u32)__shfl_xor((int)lst[7 - t], s, 64);
#pragma unroll
        for (int t = 0; t < 8; ++t) lst[t] = min(lst[t], o[t]);
        CSU(0, 4) CSU(1, 5) CSU(2, 6) CSU(3, 7)
        CSU(0, 2) CSU(1, 3) CSU(4, 6) CSU(5, 7)
        CSU(0, 1) CSU(2, 3) CSU(4, 5) CSU(6, 7)
    }

    if (lane == 0) {
#pragma unroll
        for (int t = 0; t < 8; ++t)
            idxbuf[nid * KNN + t] = (int)(lst[t] & 1023u);
    }
}

// ---------------- one EGNN layer: thread = edge, all-register MLPs, SGPR weights ----------------
__global__ __launch_bounds__(256, 2) void layer_kernel(
    const int d,
    const float* __restrict__ coordsIn, float* __restrict__ coordsOut,
    const float* __restrict__ featsIn, float* __restrict__ featsOut,
    const int* __restrict__ idxbuf, const int* __restrict__ lengths,
    const float* __restrict__ w1t, const float* __restrict__ g_eb1,
    const float* __restrict__ g_ew2, const float* __restrict__ g_eb2,
    const float* __restrict__ cw1t, const float* __restrict__ g_cb1,
    const float* __restrict__ g_cw2, const float* __restrict__ g_cb2,
    const float* __restrict__ g_lng, const float* __restrict__ g_lnb,
    const float* __restrict__ nw1t, const float* __restrict__ g_nb1,
    const float* __restrict__ nw2t, const float* __restrict__ g_nb2)
{
    const int e = blockIdx.x * 256 + threadIdx.x;   // edge id
    const int k = e & 7;                            // neighbor slot
    const int n = e >> 3;                           // global node id
    const int b = n >> 10;
    const int i = n & (SL - 1);
    const int len = lengths[b];
    const int j = idxbuf[e];
    const bool em = (i < len) && (j < len);

    // ---- load inputs into registers ----
    float fi[16], fj[16];
    {
        const float4* p = (const float4*)(featsIn + (size_t)n * DIM);
        float4 a = p[0], c2 = p[1], c3 = p[2], c4 = p[3];
        fi[0]=a.x; fi[1]=a.y; fi[2]=a.z; fi[3]=a.w;
        fi[4]=c2.x; fi[5]=c2.y; fi[6]=c2.z; fi[7]=c2.w;
        fi[8]=c3.x; fi[9]=c3.y; fi[10]=c3.z; fi[11]=c3.w;
        fi[12]=c4.x; fi[13]=c4.y; fi[14]=c4.z; fi[15]=c4.w;
    }
    {
        const float4* p = (const float4*)(featsIn + ((size_t)b * SL + j) * DIM);
        float4 a = p[0], c2 = p[1], c3 = p[2], c4 = p[3];
        fj[0]=a.x; fj[1]=a.y; fj[2]=a.z; fj[3]=a.w;
        fj[4]=c2.x; fj[5]=c2.y; fj[6]=c2.z; fj[7]=c2.w;
        fj[8]=c3.x; fj[9]=c3.y; fj[10]=c3.z; fj[11]=c3.w;
        fj[12]=c4.x; fj[13]=c4.y; fj[14]=c4.z; fj[15]=c4.w;
    }
    float ci[3], rel[3];
    {
        const float* cp = coordsIn + (size_t)n * 3;
        const float* cq = coordsIn + ((size_t)b * SL + j) * 3;
        ci[0] = cp[0]; ci[1] = cp[1]; ci[2] = cp[2];
        rel[0] = ci[0] - cq[0]; rel[1] = ci[1] - cq[1]; rel[2] = ci[2] - cq[2];
    }
    const float rd = fmaf(rel[0], rel[0], fmaf(rel[1], rel[1], rel[2] * rel[2]));

    // ---- fused edge MLP: h_u computed and immediately folded into m accumulators ----
    const float* w1base = w1t + d * EH * W1T_STRIDE;
    const float* eb1r = g_eb1 + d * EH;
    const float* w2base = g_ew2 + d * EH * MDIM;
    const float* eb2r = g_eb2 + d * MDIM;
    float macc[16];
#pragma unroll
    for (int v = 0; v < 16; ++v) macc[v] = eb2r[v];
#pragma unroll 2
    for (int u = 0; u < EH; ++u) {
        const float* wr = w1base + u * W1T_STRIDE;
        float h0 = eb1r[u], h1 = 0.f, h2 = 0.f, h3 = 0.f;
#pragma unroll
        for (int c = 0; c < 16; c += 4) {
            h0 = fmaf(fi[c + 0], wr[c + 0], h0);
            h1 = fmaf(fi[c + 1], wr[c + 1], h1);
            h2 = fmaf(fi[c + 2], wr[c + 2], h2);
            h3 = fmaf(fi[c + 3], wr[c + 3], h3);
        }
#pragma unroll
        for (int c = 0; c < 16; c += 4) {
            h0 = fmaf(fj[c + 0], wr[16 + c + 0], h0);
            h1 = fmaf(fj[c + 1], wr[16 + c + 1], h1);
            h2 = fmaf(fj[c + 2], wr[16 + c + 2], h2);
            h3 = fmaf(fj[c + 3], wr[16 + c + 3], h3);
        }
        h0 = fmaf(rd, wr[32], h0);
        const float h = silu_f((h0 + h1) + (h2 + h3));
        const float* w2r = w2base + u * MDIM;
#pragma unroll
        for (int v = 0; v < 16; ++v) macc[v] = fmaf(h, w2r[v], macc[v]);
    }
    float mm[16];
#pragma unroll
    for (int v = 0; v < 16; ++v) mm[v] = silu_f(macc[v]);

    // ---- coors MLP -> scalar weight w_e ----
    const float* cb1r = g_cb1 + d * CH;
    const float* cw2r = g_cw2 + d * CH;
    const float* c1base = cw1t + d * CH * 16;
    float wa = 0.f;
#pragma unroll 2
    for (int t = 0; t < CH; ++t) {
        const float* cr = c1base + t * 16;
        float a0 = cb1r[t], a1 = 0.f;
#pragma unroll
        for (int v = 0; v < 16; v += 2) {
            a0 = fmaf(mm[v], cr[v], a0);
            a1 = fmaf(mm[v + 1], cr[v + 1], a1);
        }
        wa = fmaf(silu_f(a0 + a1), cw2r[t], wa);
    }
    const float we = em ? (wa + g_cb2[d]) : 0.f;

    // ---- per-node reductions over the 8 edge lanes (xor butterfly) ----
    float wr0 = we * rel[0], wr1 = we * rel[1], wr2 = we * rel[2];
#pragma unroll
    for (int s = 1; s < 8; s <<= 1) {
        wr0 += __shfl_xor(wr0, s, 64);
        wr1 += __shfl_xor(wr1, s, 64);
        wr2 += __shfl_xor(wr2, s, 64);
    }
    if (k == 0) {
        coordsOut[(size_t)n * 3 + 0] = ci[0] + wr0;
        coordsOut[(size_t)n * 3 + 1] = ci[1] + wr1;
        coordsOut[(size_t)n * 3 + 2] = ci[2] + wr2;
    }
    // masked m_ij -> m_i (sum lands in every lane of the group)
#pragma unroll
    for (int v = 0; v < 16; ++v) mm[v] = em ? mm[v] : 0.f;
#pragma unroll
    for (int s = 1; s < 8; s <<= 1) {
#pragma unroll
        for (int v = 0; v < 16; ++v) mm[v] += __shfl_xor(mm[v], s, 64);
    }

    // ---- LayerNorm(fi) ----
    float mu = 0.f;
#pragma unroll
    for (int c = 0; c < 16; ++c) mu += fi[c];
    mu *= 0.0625f;
    float var = 0.f;
#pragma unroll
    for (int c = 0; c < 16; ++c) { const float dd = fi[c] - mu; var = fmaf(dd, dd, var); }
    var *= 0.0625f;
    const float rs = rsqrtf(var + LN_EPS);
    const float* lg = g_lng + d * DIM;
    const float* lb = g_lnb + d * DIM;
    float nn[16];
#pragma unroll
    for (int c = 0; c < 16; ++c) nn[c] = fmaf((fi[c] - mu) * rs, lg[c], lb[c]);

    // ---- node MLP (redundant per lane; weights uniform -> SGPR) ----
    const float* nb1r = g_nb1 + d * NHID;
    const float* n1base = nw1t + d * NHID * 32;
    float nh[32];
#pragma unroll 2
    for (int u = 0; u < NHID; ++u) {
        const float* nr = n1base + u * 32;
        float a0 = nb1r[u], a1 = 0.f;
#pragma unroll
        for (int c = 0; c < 16; c += 2) {
            a0 = fmaf(nn[c], nr[c], a0);
            a1 = fmaf(nn[c + 1], nr[c + 1], a1);
        }
#pragma unroll
        for (int v = 0; v < 16; v += 2) {
            a0 = fmaf(mm[v], nr[16 + v], a0);
            a1 = fmaf(mm[v + 1], nr[16 + v + 1], a1);
        }
        nh[u] = silu_f(a0 + a1);
    }
    const float* nb2r = g_nb2 + d * DIM;
    const float* n2base = nw2t + d * DIM * 32;
    float o0 = 0.f, o1 = 0.f;
#pragma unroll
    for (int c = 0; c < 16; c += 2) {
        const float* r0 = n2base + c * 32;
        const float* r1 = n2base + (c + 1) * 32;
        float a0 = nb2r[c], a0b = 0.f, a1 = nb2r[c + 1], a1b = 0.f;
#pragma unroll
        for (int u = 0; u < 32; u += 2) {
            a0  = fmaf(nh[u],     r0[u],     a0);
            a0b = fmaf(nh[u + 1], r0[u + 1], a0b);
            a1  = fmaf(nh[u],     r1[u],     a1);
            a1b = fmaf(nh[u + 1], r1[u + 1], a1b);
        }
        if (k == (c >> 1)) { o0 = fi[c] + (a0 + a0b); o1 = fi[c + 1] + (a1 + a1b); }
    }
    // lane k stores feats channels 2k, 2k+1 (coalesced float2)
    ((float2*)featsOut)[(size_t)n * 8 + k] = make_float2(o0, o1);
}

// ---------------- final projection ----------------
__global__ __launch_bounds__(256) void final_kernel(
    const float* __restrict__ feats, const float* __restrict__ fw,
    const float* __restrict__ fb, float* __restrict__ out)
{
    const int nid = blockIdx.x * 256 + threadIdx.x;
    if (nid >= NB * SL) return;
    float f[DIM];
#pragma unroll
    for (int c = 0; c < DIM; ++c) f[c] = feats[nid * DIM + c];
#pragma unroll
    for (int o = 0; o < 3; ++o) {
        float acc = fb[o];
#pragma unroll
        for (int c = 0; c < DIM; ++c) acc = fmaf(f[c], fw[c * 3 + o], acc);
        out[nid * 3 + o] = acc;
    }
}

extern "C" void kernel_launch(void* const* d_in, const int* in_sizes, int n_in,
                              void* d_out, int out_size, void* d_ws, size_t ws_size,
                              hipStream_t stream) {
    const float* coords    = (const float*)d_in[0];
    const int*   residues  = (const int*)d_in[1];
    const int*   lengths   = (const int*)d_in[2];
    const float* token_emb = (const float*)d_in[3];
    const float* pos_emb   = (const float*)d_in[4];
    const float* ew1 = (const float*)d_in[5];
    const float* eb1 = (const float*)d_in[6];
    const float* ew2 = (const float*)d_in[7];
    const float* eb2 = (const float*)d_in[8];
    const float* cw1 = (const float*)d_in[9];
    const float* cb1 = (const float*)d_in[10];
    const float* cw2 = (const float*)d_in[11];
    const float* cb2 = (const float*)d_in[12];
    const float* lng = (const float*)d_in[13];
    const float* lnb = (const float*)d_in[14];
    const float* nw1 = (const float*)d_in[15];
    const float* nb1 = (const float*)d_in[16];
    const float* nw2 = (const float*)d_in[17];
    const float* nb2 = (const float*)d_in[18];
    const float* fw  = (const float*)d_in[19];
    const float* fb  = (const float*)d_in[20];

    float* ws = (float*)d_ws;
    float* coordsA = ws;                              // 49152
    float* coordsB = coordsA + NB * SL * 3;           // 49152
    float* featsA  = coordsB + NB * SL * 3;           // 262144
    float* featsB  = featsA + NB * SL * DIM;          // 262144
    int*   idxbuf  = (int*)(featsB + NB * SL * DIM);  // 131072 ints
    float* w1t  = (float*)(idxbuf + NB * SL * KNN);   // 3*66*36 = 7128
    float* cw1t = w1t + 3 * EH * W1T_STRIDE;          // 3*64*16 = 3072
    float* nw1t = cw1t + 3 * CH * 16;                 // 3*32*32 = 3072
    float* nw2t = nw1t + 3 * NHID * 32;               // 3*16*32 = 1536

    pack_kernel<<<32, 256, 0, stream>>>(ew1, cw1, nw1, nw2, w1t, cw1t, nw1t, nw2t);
    init_kernel<<<NB * SL / 256, 256, 0, stream>>>(coords, residues, token_emb, pos_emb, coordsA, featsA);

    float* cIn = coordsA; float* cOut = coordsB;
    float* fIn = featsA;  float* fOut = featsB;
    for (int d = 0; d < 3; ++d) {
        knn_kernel<<<NB * SL / 4, 256, 0, stream>>>(cIn, lengths, idxbuf);
        layer_kernel<<<NB * SL * KNN / 256, 256, 0, stream>>>(d, cIn, cOut, fIn, fOut, idxbuf, lengths,
            w1t, eb1, ew2, eb2, cw1t, cb1, cw2, cb2, lng, lnb, nw1t, nb1, nw2t, nb2);
        float* t;
        t = cIn; cIn = cOut; cOut = t;
        t = fIn; fIn = fOut; fOut = t;
    }

    final_kernel<<<NB * SL / 256, 256, 0, stream>>>(fIn, fw, fb, (float*)d_out);
}